// Round 1
// baseline (192.190 us; speedup 1.0000x reference)
//
#include <hip/hip_runtime.h>
#include <hip/hip_bf16.h>

#define N 8192
#define NH 8
#define BLK 256
#define NWAVES (BLK / 64)

// ---- JAX Threefry-2x32, key = (0, 42)  (jax.random.key(42)) ----
// Partitionable mode: element m uses counter words (hi, lo) = (0, m),
// output bits = x0 ^ x1 after 20 rounds.
__device__ __forceinline__ unsigned rotl32(unsigned x, unsigned r) {
  return (x << r) | (x >> (32u - r));
}

__device__ __forceinline__ unsigned threefry_bits(unsigned m) {
  const unsigned ks0 = 0u;
  const unsigned ks1 = 42u;
  const unsigned ks2 = 0x1BD11BDAu ^ ks0 ^ ks1;  // 0x1BD11BF0
  unsigned x0 = 0u + ks0;   // counter hi word = 0
  unsigned x1 = m + ks1;    // counter lo word = m
#define TF_R4(ra, rb, rc, rd)                          \
  x0 += x1; x1 = rotl32(x1, ra); x1 ^= x0;             \
  x0 += x1; x1 = rotl32(x1, rb); x1 ^= x0;             \
  x0 += x1; x1 = rotl32(x1, rc); x1 ^= x0;             \
  x0 += x1; x1 = rotl32(x1, rd); x1 ^= x0;
  TF_R4(13u, 15u, 26u, 6u)  x0 += ks1; x1 += ks2 + 1u;
  TF_R4(17u, 29u, 16u, 24u) x0 += ks2; x1 += ks0 + 2u;
  TF_R4(13u, 15u, 26u, 6u)  x0 += ks0; x1 += ks1 + 3u;
  TF_R4(17u, 29u, 16u, 24u) x0 += ks1; x1 += ks2 + 4u;
  TF_R4(13u, 15u, 26u, 6u)  x0 += ks2; x1 += ks0 + 5u;
#undef TF_R4
  return x0 ^ x1;
}

// One block per output row i.
// out[i,h] = w_v[h] * S_i / (0.9 * Z_i)
__global__ __launch_bounds__(BLK) void fused_attn_kernel(
    const float* __restrict__ x1, const float* __restrict__ x2,
    const float* __restrict__ w_q, const float* __restrict__ w_k,
    const float* __restrict__ w_v, float* __restrict__ out) {
  const int tid = threadIdx.x;
  const int i = blockIdx.x;

  // c = sum_h w_q[h]*w_k[h]   (broadcast loads, redundant per thread)
  float c = 0.f;
#pragma unroll
  for (int h = 0; h < NH; ++h) c += w_q[h] * w_k[h];

  // pass 1: max/min of x2 (row-max of scores is a*max(x2) or a*min(x2))
  float mx = -3.402823466e38f, mn = 3.402823466e38f;
  for (int j = tid; j < N; j += BLK) {
    float v = x2[j];
    mx = fmaxf(mx, v);
    mn = fminf(mn, v);
  }
#pragma unroll
  for (int off = 32; off > 0; off >>= 1) {
    mx = fmaxf(mx, __shfl_down(mx, off));
    mn = fminf(mn, __shfl_down(mn, off));
  }
  __shared__ float smx[NWAVES], smn[NWAVES], sbc[2];
  if ((tid & 63) == 0) { smx[tid >> 6] = mx; smn[tid >> 6] = mn; }
  __syncthreads();
  if (tid == 0) {
    mx = smx[0]; mn = smn[0];
    for (int w = 1; w < NWAVES; ++w) {
      mx = fmaxf(mx, smx[w]);
      mn = fminf(mn, smn[w]);
    }
    sbc[0] = mx; sbc[1] = mn;
  }
  __syncthreads();
  mx = sbc[0]; mn = sbc[1];

  const float a  = c * x1[i];
  const float L2E = 1.4426950408889634f;
  const float a2 = a * L2E;                       // fold log2(e): exp(x)=exp2(x*L2E)
  const float m2 = (a >= 0.f ? mx : mn) * a2;     // row max in exp2 domain

  float zacc = 0.f, sacc = 0.f;
  const unsigned base = (unsigned)i * (unsigned)N;
#pragma unroll 4
  for (int j = tid; j < N; j += BLK) {
    float p = exp2f(fmaf(a2, x2[j], -m2));        // exp(score - max)
    unsigned bits = threefry_bits(base + (unsigned)j);
    float u = __uint_as_float((bits >> 9) | 0x3F800000u) - 1.0f;  // uniform [0,1)
    zacc += p;
    sacc += (u < 0.9f) ? p * x1[j] : 0.f;
  }
#pragma unroll
  for (int off = 32; off > 0; off >>= 1) {
    zacc += __shfl_down(zacc, off);
    sacc += __shfl_down(sacc, off);
  }
  __shared__ float sz[NWAVES], ss[NWAVES], st;
  if ((tid & 63) == 0) { sz[tid >> 6] = zacc; ss[tid >> 6] = sacc; }
  __syncthreads();
  if (tid == 0) {
    float z = 0.f, s = 0.f;
    for (int w = 0; w < NWAVES; ++w) { z += sz[w]; s += ss[w]; }
    st = s / (0.9f * z);
  }
  __syncthreads();
  if (tid < NH) out[i * NH + tid] = w_v[tid] * st;
}

extern "C" void kernel_launch(void* const* d_in, const int* in_sizes, int n_in,
                              void* d_out, int out_size, void* d_ws, size_t ws_size,
                              hipStream_t stream) {
  const float* x1  = (const float*)d_in[0];
  const float* x2  = (const float*)d_in[1];
  const float* w_q = (const float*)d_in[2];
  const float* w_k = (const float*)d_in[3];
  const float* w_v = (const float*)d_in[4];
  float* out = (float*)d_out;
  fused_attn_kernel<<<dim3(N), dim3(BLK), 0, stream>>>(x1, x2, w_q, w_k, w_v, out);
}

// Round 2
// 173.720 us; speedup vs baseline: 1.1063x; 1.1063x over previous
//
#include <hip/hip_runtime.h>
#include <hip/hip_bf16.h>

#define N 8192
#define NH 8
#define BLK 256
#define NWAVES (BLK / 64)
#define KS2 0x1BD11BF0u  // 0x1BD11BDA ^ 0 ^ 42

// JAX Threefry-2x32, key=(0,42), partitionable: counter=(0,m), bits=x0^x1.
// Input here is m+42 (ks1 pre-folded by caller).
__device__ __forceinline__ unsigned tf_bits(unsigned m42) {
  unsigned x0 = m42;  // x0=0+ks0, then round-1 "x0+=x1" gives x0=x1
  unsigned x1 = m42;
  x1 = __builtin_rotateleft32(x1, 13) ^ x0;
  x0 += x1; x1 = __builtin_rotateleft32(x1, 15) ^ x0;
  x0 += x1; x1 = __builtin_rotateleft32(x1, 26) ^ x0;
  x0 += x1; x1 = __builtin_rotateleft32(x1,  6) ^ x0;
  x0 += 42u;  x1 += KS2 + 1u;
  x0 += x1; x1 = __builtin_rotateleft32(x1, 17) ^ x0;
  x0 += x1; x1 = __builtin_rotateleft32(x1, 29) ^ x0;
  x0 += x1; x1 = __builtin_rotateleft32(x1, 16) ^ x0;
  x0 += x1; x1 = __builtin_rotateleft32(x1, 24) ^ x0;
  x0 += KS2; x1 += 2u;
  x0 += x1; x1 = __builtin_rotateleft32(x1, 13) ^ x0;
  x0 += x1; x1 = __builtin_rotateleft32(x1, 15) ^ x0;
  x0 += x1; x1 = __builtin_rotateleft32(x1, 26) ^ x0;
  x0 += x1; x1 = __builtin_rotateleft32(x1,  6) ^ x0;
  /* x0 += 0 */ x1 += 45u;
  x0 += x1; x1 = __builtin_rotateleft32(x1, 17) ^ x0;
  x0 += x1; x1 = __builtin_rotateleft32(x1, 29) ^ x0;
  x0 += x1; x1 = __builtin_rotateleft32(x1, 16) ^ x0;
  x0 += x1; x1 = __builtin_rotateleft32(x1, 24) ^ x0;
  x0 += 42u;  x1 += KS2 + 4u;
  x0 += x1; x1 = __builtin_rotateleft32(x1, 13) ^ x0;
  x0 += x1; x1 = __builtin_rotateleft32(x1, 15) ^ x0;
  x0 += x1; x1 = __builtin_rotateleft32(x1, 26) ^ x0;
  x0 += x1; x1 = __builtin_rotateleft32(x1,  6) ^ x0;
  x0 += KS2; x1 += 5u;
  return x0 ^ x1;
}

// One block per output row i.  out[i,h] = w_v[h] * S_i / (0.9 * Z_i)
__global__ __launch_bounds__(BLK) void fused_attn_kernel(
    const float* __restrict__ x1, const float* __restrict__ x2,
    const float* __restrict__ w_q, const float* __restrict__ w_k,
    const float* __restrict__ w_v, float* __restrict__ out) {
  const int tid = threadIdx.x;
  const int i = blockIdx.x;

  float c = 0.f;
#pragma unroll
  for (int h = 0; h < NH; ++h) c += w_q[h] * w_k[h];

  const float4* __restrict__ x2v = (const float4*)x2;
  const float4* __restrict__ x1v = (const float4*)x1;

  // pass 1: max/min of x2 (row max of scores = a*max(x2) or a*min(x2))
  float mx = -3.402823466e38f, mn = 3.402823466e38f;
#pragma unroll
  for (int c4 = 0; c4 < N / 4 / BLK; ++c4) {
    float4 v = x2v[tid + c4 * BLK];
    mx = fmaxf(fmaxf(fmaxf(mx, v.x), fmaxf(v.y, v.z)), v.w);
    mn = fminf(fminf(fminf(mn, v.x), fminf(v.y, v.z)), v.w);
  }
#pragma unroll
  for (int off = 32; off > 0; off >>= 1) {
    mx = fmaxf(mx, __shfl_down(mx, off));
    mn = fminf(mn, __shfl_down(mn, off));
  }
  __shared__ float smx[NWAVES], smn[NWAVES], sbc[2];
  if ((tid & 63) == 0) { smx[tid >> 6] = mx; smn[tid >> 6] = mn; }
  __syncthreads();
  if (tid == 0) {
    mx = smx[0]; mn = smn[0];
    for (int w = 1; w < NWAVES; ++w) {
      mx = fmaxf(mx, smx[w]);
      mn = fminf(mn, smn[w]);
    }
    sbc[0] = mx; sbc[1] = mn;
  }
  __syncthreads();
  mx = sbc[0]; mn = sbc[1];

  const float a   = c * x1[i];
  const float a2  = a * 1.4426950408889634f;       // exp(x) = exp2(x*log2e)
  const float nm2 = -((a >= 0.f ? mx : mn) * a2);  // -(row max), exp2 domain

  float zacc = 0.f, sacc = 0.f;
  const unsigned mbase = (unsigned)i * (unsigned)N + 42u;  // fold ks1=42

#pragma unroll 2
  for (int c4 = 0; c4 < N / 4 / BLK; ++c4) {
    const int j4 = tid + c4 * BLK;
    const float4 xv = x2v[j4];
    const float4 yv = x1v[j4];
    const unsigned m0 = mbase + 4u * (unsigned)j4;

    // elem 0
    {
      float p = exp2f(fmaf(a2, xv.x, nm2));
      zacc += p;
      float t = (tf_bits(m0 + 0u) < 0xE6666600u) ? yv.x : 0.f;
      sacc = fmaf(p, t, sacc);
    }
    // elem 1
    {
      float p = exp2f(fmaf(a2, xv.y, nm2));
      zacc += p;
      float t = (tf_bits(m0 + 1u) < 0xE6666600u) ? yv.y : 0.f;
      sacc = fmaf(p, t, sacc);
    }
    // elem 2
    {
      float p = exp2f(fmaf(a2, xv.z, nm2));
      zacc += p;
      float t = (tf_bits(m0 + 2u) < 0xE6666600u) ? yv.z : 0.f;
      sacc = fmaf(p, t, sacc);
    }
    // elem 3
    {
      float p = exp2f(fmaf(a2, xv.w, nm2));
      zacc += p;
      float t = (tf_bits(m0 + 3u) < 0xE6666600u) ? yv.w : 0.f;
      sacc = fmaf(p, t, sacc);
    }
  }

#pragma unroll
  for (int off = 32; off > 0; off >>= 1) {
    zacc += __shfl_down(zacc, off);
    sacc += __shfl_down(sacc, off);
  }
  __shared__ float sz[NWAVES], ss[NWAVES], st;
  if ((tid & 63) == 0) { sz[tid >> 6] = zacc; ss[tid >> 6] = sacc; }
  __syncthreads();
  if (tid == 0) {
    float z = 0.f, s = 0.f;
    for (int w = 0; w < NWAVES; ++w) { z += sz[w]; s += ss[w]; }
    st = s / (0.9f * z);
  }
  __syncthreads();
  if (tid < NH) out[i * NH + tid] = w_v[tid] * st;
}

extern "C" void kernel_launch(void* const* d_in, const int* in_sizes, int n_in,
                              void* d_out, int out_size, void* d_ws, size_t ws_size,
                              hipStream_t stream) {
  const float* x1  = (const float*)d_in[0];
  const float* x2  = (const float*)d_in[1];
  const float* w_q = (const float*)d_in[2];
  const float* w_k = (const float*)d_in[3];
  const float* w_v = (const float*)d_in[4];
  float* out = (float*)d_out;
  fused_attn_kernel<<<dim3(N), dim3(BLK), 0, stream>>>(x1, x2, w_q, w_k, w_v, out);
}

// Round 3
// 142.881 us; speedup vs baseline: 1.3451x; 1.2158x over previous
//
#include <hip/hip_runtime.h>
#include <hip/hip_bf16.h>

#define N 8192
#define NH 8
#define BLK 256
#define NWAVES (BLK / 64)

// JAX Threefry-2x32, key=(0,42), partitionable mode: counter=(0,m), bits=x0^x1.
// Input is m+42 (ks1 pre-folded). Hand-scheduled: 69 VALU instrs exactly.
// rotl(r) == v_alignbit_b32 x,x,x,(32-r). Key schedule: ks0=0, ks1=42,
// ks2=0x1BD11BF0. Injections after each 4-round group:
//  G1: x0+=42,          x1+=0x1BD11BF1
//  G2: x0+=0x1BD11BF0,  x1+=2
//  G3: x0+=0 (elided),  x1+=45
//  G4: x0+=42,          x1+=0x1BD11BF4
//  G5: x0+=0x1BD11BF0,  x1+=5
__device__ __forceinline__ unsigned tf_bits_asm(unsigned m42) {
  unsigned x0 = m42, x1 = m42;  // x0 = 0+ks0 then round-1 "x0+=x1" elided
  asm(
    // G1: rotl 13,15,26,6  -> shifts 19,17,6,26   (first add elided)
    "v_alignbit_b32 %1, %1, %1, 19\n\t"
    "v_xor_b32 %1, %1, %0\n\t"
    "v_add_u32 %0, %0, %1\n\t"
    "v_alignbit_b32 %1, %1, %1, 17\n\t"
    "v_xor_b32 %1, %1, %0\n\t"
    "v_add_u32 %0, %0, %1\n\t"
    "v_alignbit_b32 %1, %1, %1, 6\n\t"
    "v_xor_b32 %1, %1, %0\n\t"
    "v_add_u32 %0, %0, %1\n\t"
    "v_alignbit_b32 %1, %1, %1, 26\n\t"
    "v_xor_b32 %1, %1, %0\n\t"
    "v_add_u32 %0, 42, %0\n\t"
    "v_add_u32 %1, 0x1bd11bf1, %1\n\t"
    // G2: rotl 17,29,16,24 -> shifts 15,3,16,8
    "v_add_u32 %0, %0, %1\n\t"
    "v_alignbit_b32 %1, %1, %1, 15\n\t"
    "v_xor_b32 %1, %1, %0\n\t"
    "v_add_u32 %0, %0, %1\n\t"
    "v_alignbit_b32 %1, %1, %1, 3\n\t"
    "v_xor_b32 %1, %1, %0\n\t"
    "v_add_u32 %0, %0, %1\n\t"
    "v_alignbit_b32 %1, %1, %1, 16\n\t"
    "v_xor_b32 %1, %1, %0\n\t"
    "v_add_u32 %0, %0, %1\n\t"
    "v_alignbit_b32 %1, %1, %1, 8\n\t"
    "v_xor_b32 %1, %1, %0\n\t"
    "v_add_u32 %0, 0x1bd11bf0, %0\n\t"
    "v_add_u32 %1, 2, %1\n\t"
    // G3: rotl 13,15,26,6
    "v_add_u32 %0, %0, %1\n\t"
    "v_alignbit_b32 %1, %1, %1, 19\n\t"
    "v_xor_b32 %1, %1, %0\n\t"
    "v_add_u32 %0, %0, %1\n\t"
    "v_alignbit_b32 %1, %1, %1, 17\n\t"
    "v_xor_b32 %1, %1, %0\n\t"
    "v_add_u32 %0, %0, %1\n\t"
    "v_alignbit_b32 %1, %1, %1, 6\n\t"
    "v_xor_b32 %1, %1, %0\n\t"
    "v_add_u32 %0, %0, %1\n\t"
    "v_alignbit_b32 %1, %1, %1, 26\n\t"
    "v_xor_b32 %1, %1, %0\n\t"
    "v_add_u32 %1, 45, %1\n\t"
    // G4: rotl 17,29,16,24
    "v_add_u32 %0, %0, %1\n\t"
    "v_alignbit_b32 %1, %1, %1, 15\n\t"
    "v_xor_b32 %1, %1, %0\n\t"
    "v_add_u32 %0, %0, %1\n\t"
    "v_alignbit_b32 %1, %1, %1, 3\n\t"
    "v_xor_b32 %1, %1, %0\n\t"
    "v_add_u32 %0, %0, %1\n\t"
    "v_alignbit_b32 %1, %1, %1, 16\n\t"
    "v_xor_b32 %1, %1, %0\n\t"
    "v_add_u32 %0, %0, %1\n\t"
    "v_alignbit_b32 %1, %1, %1, 8\n\t"
    "v_xor_b32 %1, %1, %0\n\t"
    "v_add_u32 %0, 42, %0\n\t"
    "v_add_u32 %1, 0x1bd11bf4, %1\n\t"
    // G5: rotl 13,15,26,6
    "v_add_u32 %0, %0, %1\n\t"
    "v_alignbit_b32 %1, %1, %1, 19\n\t"
    "v_xor_b32 %1, %1, %0\n\t"
    "v_add_u32 %0, %0, %1\n\t"
    "v_alignbit_b32 %1, %1, %1, 17\n\t"
    "v_xor_b32 %1, %1, %0\n\t"
    "v_add_u32 %0, %0, %1\n\t"
    "v_alignbit_b32 %1, %1, %1, 6\n\t"
    "v_xor_b32 %1, %1, %0\n\t"
    "v_add_u32 %0, %0, %1\n\t"
    "v_alignbit_b32 %1, %1, %1, 26\n\t"
    "v_xor_b32 %1, %1, %0\n\t"
    "v_add_u32 %0, 0x1bd11bf0, %0\n\t"
    "v_add_u32 %1, 5, %1\n\t"
    "v_xor_b32 %0, %0, %1"
    : "+v"(x0), "+v"(x1));
  return x0;
}

// One block per output row i.  out[i,h] = w_v[h] * S_i / (0.9 * Z_i)
__global__ __launch_bounds__(BLK) void fused_attn_kernel(
    const float* __restrict__ x1, const float* __restrict__ x2,
    const float* __restrict__ w_q, const float* __restrict__ w_k,
    const float* __restrict__ w_v, float* __restrict__ out) {
  const int tid = threadIdx.x;
  const int i = blockIdx.x;

  float c = 0.f;
#pragma unroll
  for (int h = 0; h < NH; ++h) c += w_q[h] * w_k[h];

  const float4* __restrict__ x2v = (const float4*)x2;
  const float4* __restrict__ x1v = (const float4*)x1;

  // pass 1: max/min of x2 (row max of scores = a*max(x2) or a*min(x2))
  float mx = -3.402823466e38f, mn = 3.402823466e38f;
#pragma unroll
  for (int c4 = 0; c4 < N / 4 / BLK; ++c4) {
    float4 v = x2v[tid + c4 * BLK];
    mx = fmaxf(fmaxf(fmaxf(mx, v.x), fmaxf(v.y, v.z)), v.w);
    mn = fminf(fminf(fminf(mn, v.x), fminf(v.y, v.z)), v.w);
  }
#pragma unroll
  for (int off = 32; off > 0; off >>= 1) {
    mx = fmaxf(mx, __shfl_down(mx, off));
    mn = fminf(mn, __shfl_down(mn, off));
  }
  __shared__ float smx[NWAVES], smn[NWAVES], sbc[2];
  if ((tid & 63) == 0) { smx[tid >> 6] = mx; smn[tid >> 6] = mn; }
  __syncthreads();
  if (tid == 0) {
    mx = smx[0]; mn = smn[0];
    for (int w = 1; w < NWAVES; ++w) {
      mx = fmaxf(mx, smx[w]);
      mn = fminf(mn, smn[w]);
    }
    sbc[0] = mx; sbc[1] = mn;
  }
  __syncthreads();
  mx = sbc[0]; mn = sbc[1];

  const float a   = c * x1[i];
  const float a2  = a * 1.4426950408889634f;       // exp(x) = exp2(x*log2e)
  const float nm2 = -((a >= 0.f ? mx : mn) * a2);  // -(row max), exp2 domain

  float zacc = 0.f, sacc = 0.f;
  const unsigned mbase = (unsigned)i * (unsigned)N + 42u;  // fold ks1=42

#pragma unroll 2
  for (int c4 = 0; c4 < N / 4 / BLK; ++c4) {
    const int j4 = tid + c4 * BLK;
    const float4 xv = x2v[j4];
    const float4 yv = x1v[j4];
    const unsigned m0 = mbase + 4u * (unsigned)j4;

    {
      float p = __builtin_amdgcn_exp2f(fmaf(a2, xv.x, nm2));
      zacc += p;
      float t = (tf_bits_asm(m0 + 0u) < 0xE6666600u) ? yv.x : 0.f;
      sacc = fmaf(p, t, sacc);
    }
    {
      float p = __builtin_amdgcn_exp2f(fmaf(a2, xv.y, nm2));
      zacc += p;
      float t = (tf_bits_asm(m0 + 1u) < 0xE6666600u) ? yv.y : 0.f;
      sacc = fmaf(p, t, sacc);
    }
    {
      float p = __builtin_amdgcn_exp2f(fmaf(a2, xv.z, nm2));
      zacc += p;
      float t = (tf_bits_asm(m0 + 2u) < 0xE6666600u) ? yv.z : 0.f;
      sacc = fmaf(p, t, sacc);
    }
    {
      float p = __builtin_amdgcn_exp2f(fmaf(a2, xv.w, nm2));
      zacc += p;
      float t = (tf_bits_asm(m0 + 3u) < 0xE6666600u) ? yv.w : 0.f;
      sacc = fmaf(p, t, sacc);
    }
  }

#pragma unroll
  for (int off = 32; off > 0; off >>= 1) {
    zacc += __shfl_down(zacc, off);
    sacc += __shfl_down(sacc, off);
  }
  __shared__ float sz[NWAVES], ss[NWAVES], st;
  if ((tid & 63) == 0) { sz[tid >> 6] = zacc; ss[tid >> 6] = sacc; }
  __syncthreads();
  if (tid == 0) {
    float z = 0.f, s = 0.f;
    for (int w = 0; w < NWAVES; ++w) { z += sz[w]; s += ss[w]; }
    st = s / (0.9f * z);
  }
  __syncthreads();
  if (tid < NH) out[i * NH + tid] = w_v[tid] * st;
}

extern "C" void kernel_launch(void* const* d_in, const int* in_sizes, int n_in,
                              void* d_out, int out_size, void* d_ws, size_t ws_size,
                              hipStream_t stream) {
  const float* x1  = (const float*)d_in[0];
  const float* x2  = (const float*)d_in[1];
  const float* w_q = (const float*)d_in[2];
  const float* w_k = (const float*)d_in[3];
  const float* w_v = (const float*)d_in[4];
  float* out = (float*)d_out;
  fused_attn_kernel<<<dim3(N), dim3(BLK), 0, stream>>>(x1, x2, w_q, w_k, w_v, out);
}

// Round 4
// 140.010 us; speedup vs baseline: 1.3727x; 1.0205x over previous
//
#include <hip/hip_runtime.h>
#include <hip/hip_bf16.h>

#define N 8192
#define NH 8
#define BLK 256
#define NWAVES (BLK / 64)

// JAX Threefry-2x32, key=(0,42), partitionable mode: counter=(0,m), bits=x0^x1.
// Input is m+42 (ks1 pre-folded). 66 VALU instrs: injection adds merged into
// the following round-add via v_add3_u32; first round-add and x0/x1 dup elided.
// ks2s must hold 0x1BD11BF0 (kept in an SGPR; add3 allows 1 SGPR operand).
__device__ __forceinline__ unsigned tf_bits_asm(unsigned m42, unsigned ks2s) {
  unsigned x0, x1;
  asm(
    // G1: rotl 13,15,26,6 -> alignbit shifts 19,17,6,26 (first add elided)
    "v_alignbit_b32 %1, %2, %2, 19\n\t"
    "v_xor_b32 %1, %1, %2\n\t"
    "v_add_u32 %0, %2, %1\n\t"
    "v_alignbit_b32 %1, %1, %1, 17\n\t"
    "v_xor_b32 %1, %1, %0\n\t"
    "v_add_u32 %0, %0, %1\n\t"
    "v_alignbit_b32 %1, %1, %1, 6\n\t"
    "v_xor_b32 %1, %1, %0\n\t"
    "v_add_u32 %0, %0, %1\n\t"
    "v_alignbit_b32 %1, %1, %1, 26\n\t"
    "v_xor_b32 %1, %1, %0\n\t"
    // inject1 (x0+=42, x1+=0x1bd11bf1) merged with round-5 add
    "v_add_u32 %1, 0x1bd11bf1, %1\n\t"
    "v_add3_u32 %0, %0, %1, 42\n\t"
    // G2: rotl 17,29,16,24 -> shifts 15,3,16,8
    "v_alignbit_b32 %1, %1, %1, 15\n\t"
    "v_xor_b32 %1, %1, %0\n\t"
    "v_add_u32 %0, %0, %1\n\t"
    "v_alignbit_b32 %1, %1, %1, 3\n\t"
    "v_xor_b32 %1, %1, %0\n\t"
    "v_add_u32 %0, %0, %1\n\t"
    "v_alignbit_b32 %1, %1, %1, 16\n\t"
    "v_xor_b32 %1, %1, %0\n\t"
    "v_add_u32 %0, %0, %1\n\t"
    "v_alignbit_b32 %1, %1, %1, 8\n\t"
    "v_xor_b32 %1, %1, %0\n\t"
    // inject2 (x0+=ks2, x1+=2) merged
    "v_add_u32 %1, 2, %1\n\t"
    "v_add3_u32 %0, %0, %1, %3\n\t"
    // G3: shifts 19,17,6,26
    "v_alignbit_b32 %1, %1, %1, 19\n\t"
    "v_xor_b32 %1, %1, %0\n\t"
    "v_add_u32 %0, %0, %1\n\t"
    "v_alignbit_b32 %1, %1, %1, 17\n\t"
    "v_xor_b32 %1, %1, %0\n\t"
    "v_add_u32 %0, %0, %1\n\t"
    "v_alignbit_b32 %1, %1, %1, 6\n\t"
    "v_xor_b32 %1, %1, %0\n\t"
    "v_add_u32 %0, %0, %1\n\t"
    "v_alignbit_b32 %1, %1, %1, 26\n\t"
    "v_xor_b32 %1, %1, %0\n\t"
    // inject3 (x0+=0, x1+=45); round-13 add normal
    "v_add_u32 %1, 45, %1\n\t"
    "v_add_u32 %0, %0, %1\n\t"
    // G4: shifts 15,3,16,8
    "v_alignbit_b32 %1, %1, %1, 15\n\t"
    "v_xor_b32 %1, %1, %0\n\t"
    "v_add_u32 %0, %0, %1\n\t"
    "v_alignbit_b32 %1, %1, %1, 3\n\t"
    "v_xor_b32 %1, %1, %0\n\t"
    "v_add_u32 %0, %0, %1\n\t"
    "v_alignbit_b32 %1, %1, %1, 16\n\t"
    "v_xor_b32 %1, %1, %0\n\t"
    "v_add_u32 %0, %0, %1\n\t"
    "v_alignbit_b32 %1, %1, %1, 8\n\t"
    "v_xor_b32 %1, %1, %0\n\t"
    // inject4 (x0+=42, x1+=0x1bd11bf4) merged
    "v_add_u32 %1, 0x1bd11bf4, %1\n\t"
    "v_add3_u32 %0, %0, %1, 42\n\t"
    // G5: shifts 19,17,6,26
    "v_alignbit_b32 %1, %1, %1, 19\n\t"
    "v_xor_b32 %1, %1, %0\n\t"
    "v_add_u32 %0, %0, %1\n\t"
    "v_alignbit_b32 %1, %1, %1, 17\n\t"
    "v_xor_b32 %1, %1, %0\n\t"
    "v_add_u32 %0, %0, %1\n\t"
    "v_alignbit_b32 %1, %1, %1, 6\n\t"
    "v_xor_b32 %1, %1, %0\n\t"
    "v_add_u32 %0, %0, %1\n\t"
    "v_alignbit_b32 %1, %1, %1, 26\n\t"
    "v_xor_b32 %1, %1, %0\n\t"
    // final inject + output xor: out = (x0+ks2) ^ (x1+5)
    "v_add_u32 %0, %3, %0\n\t"
    "v_add_u32 %1, 5, %1\n\t"
    "v_xor_b32 %0, %0, %1"
    : "=&v"(x0), "=&v"(x1)
    : "v"(m42), "s"(ks2s));
  return x0;
}

// One block per output row i.  out[i,h] = w_v[h] * S_i / (0.9 * Z_i)
__global__ __launch_bounds__(BLK) void fused_attn_kernel(
    const float* __restrict__ x1, const float* __restrict__ x2,
    const float* __restrict__ w_q, const float* __restrict__ w_k,
    const float* __restrict__ w_v, float* __restrict__ out) {
  const int tid = threadIdx.x;
  const int i = blockIdx.x;
  const unsigned ks2 = 0x1BD11BF0u;  // uniform -> SGPR

  float c = 0.f;
#pragma unroll
  for (int h = 0; h < NH; ++h) c += w_q[h] * w_k[h];

  const float4* __restrict__ x2v = (const float4*)x2;
  const float4* __restrict__ x1v = (const float4*)x1;

  // pass 1: max/min of x2 (row max of scores = a*max(x2) or a*min(x2))
  float mx = -3.402823466e38f, mn = 3.402823466e38f;
#pragma unroll
  for (int c4 = 0; c4 < N / 4 / BLK; ++c4) {
    float4 v = x2v[tid + c4 * BLK];
    mx = fmaxf(fmaxf(fmaxf(mx, v.x), fmaxf(v.y, v.z)), v.w);
    mn = fminf(fminf(fminf(mn, v.x), fminf(v.y, v.z)), v.w);
  }
#pragma unroll
  for (int off = 32; off > 0; off >>= 1) {
    mx = fmaxf(mx, __shfl_down(mx, off));
    mn = fminf(mn, __shfl_down(mn, off));
  }
  __shared__ float smx[NWAVES], smn[NWAVES], sbc[2];
  if ((tid & 63) == 0) { smx[tid >> 6] = mx; smn[tid >> 6] = mn; }
  __syncthreads();
  if (tid == 0) {
    mx = smx[0]; mn = smn[0];
    for (int w = 1; w < NWAVES; ++w) {
      mx = fmaxf(mx, smx[w]);
      mn = fminf(mn, smn[w]);
    }
    sbc[0] = mx; sbc[1] = mn;
  }
  __syncthreads();
  mx = sbc[0]; mn = sbc[1];

  const float a   = c * x1[i];
  const float a2  = a * 1.4426950408889634f;       // exp(x) = exp2(x*log2e)
  const float nm2 = -((a >= 0.f ? mx : mn) * a2);  // -(row max), exp2 domain

  float zacc = 0.f, sacc = 0.f;
  const unsigned mbase = (unsigned)i * (unsigned)N + 42u;  // fold ks1=42

#pragma unroll 2
  for (int c4 = 0; c4 < N / 4 / BLK; ++c4) {
    const int j4 = tid + c4 * BLK;
    const float4 xv = x2v[j4];
    const float4 yv = x1v[j4];
    const unsigned m0 = mbase + 4u * (unsigned)j4;

    {
      float p = __builtin_amdgcn_exp2f(fmaf(a2, xv.x, nm2));
      zacc += p;
      float t = (tf_bits_asm(m0 + 0u, ks2) < 0xE6666600u) ? yv.x : 0.f;
      sacc = fmaf(p, t, sacc);
    }
    {
      float p = __builtin_amdgcn_exp2f(fmaf(a2, xv.y, nm2));
      zacc += p;
      float t = (tf_bits_asm(m0 + 1u, ks2) < 0xE6666600u) ? yv.y : 0.f;
      sacc = fmaf(p, t, sacc);
    }
    {
      float p = __builtin_amdgcn_exp2f(fmaf(a2, xv.z, nm2));
      zacc += p;
      float t = (tf_bits_asm(m0 + 2u, ks2) < 0xE6666600u) ? yv.z : 0.f;
      sacc = fmaf(p, t, sacc);
    }
    {
      float p = __builtin_amdgcn_exp2f(fmaf(a2, xv.w, nm2));
      zacc += p;
      float t = (tf_bits_asm(m0 + 3u, ks2) < 0xE6666600u) ? yv.w : 0.f;
      sacc = fmaf(p, t, sacc);
    }
  }

#pragma unroll
  for (int off = 32; off > 0; off >>= 1) {
    zacc += __shfl_down(zacc, off);
    sacc += __shfl_down(sacc, off);
  }
  __shared__ float sz[NWAVES], ss[NWAVES], st;
  if ((tid & 63) == 0) { sz[tid >> 6] = zacc; ss[tid >> 6] = sacc; }
  __syncthreads();
  if (tid == 0) {
    float z = 0.f, s = 0.f;
    for (int w = 0; w < NWAVES; ++w) { z += sz[w]; s += ss[w]; }
    st = s / (0.9f * z);
  }
  __syncthreads();
  if (tid < NH) out[i * NH + tid] = w_v[tid] * st;
}

extern "C" void kernel_launch(void* const* d_in, const int* in_sizes, int n_in,
                              void* d_out, int out_size, void* d_ws, size_t ws_size,
                              hipStream_t stream) {
  const float* x1  = (const float*)d_in[0];
  const float* x2  = (const float*)d_in[1];
  const float* w_q = (const float*)d_in[2];
  const float* w_k = (const float*)d_in[3];
  const float* w_v = (const float*)d_in[4];
  float* out = (float*)d_out;
  fused_attn_kernel<<<dim3(N), dim3(BLK), 0, stream>>>(x1, x2, w_q, w_k, w_v, out);
}

// Round 5
// 133.697 us; speedup vs baseline: 1.4375x; 1.0472x over previous
//
#include <hip/hip_runtime.h>
#include <hip/hip_bf16.h>

#define N 8192
#define NH 8
#define BLK 256
#define NWAVES (BLK / 64)

// JAX Threefry-2x32, key=(0,42), partitionable mode: counter=(0,m), bits=x0^x1.
// Input is m+42 (ks1 pre-folded). 66 VALU instrs; injection adds merged into
// the following round-add via v_add3_u32; first round-add and x0/x1 dup elided.
// ks2s must hold 0x1BD11BF0 (SGPR; v_add3 allows 1 SGPR operand).
__device__ __forceinline__ unsigned tf_bits_asm(unsigned m42, unsigned ks2s) {
  unsigned x0, x1;
  asm(
    "v_alignbit_b32 %1, %2, %2, 19\n\t"
    "v_xor_b32 %1, %1, %2\n\t"
    "v_add_u32 %0, %2, %1\n\t"
    "v_alignbit_b32 %1, %1, %1, 17\n\t"
    "v_xor_b32 %1, %1, %0\n\t"
    "v_add_u32 %0, %0, %1\n\t"
    "v_alignbit_b32 %1, %1, %1, 6\n\t"
    "v_xor_b32 %1, %1, %0\n\t"
    "v_add_u32 %0, %0, %1\n\t"
    "v_alignbit_b32 %1, %1, %1, 26\n\t"
    "v_xor_b32 %1, %1, %0\n\t"
    "v_add_u32 %1, 0x1bd11bf1, %1\n\t"
    "v_add3_u32 %0, %0, %1, 42\n\t"
    "v_alignbit_b32 %1, %1, %1, 15\n\t"
    "v_xor_b32 %1, %1, %0\n\t"
    "v_add_u32 %0, %0, %1\n\t"
    "v_alignbit_b32 %1, %1, %1, 3\n\t"
    "v_xor_b32 %1, %1, %0\n\t"
    "v_add_u32 %0, %0, %1\n\t"
    "v_alignbit_b32 %1, %1, %1, 16\n\t"
    "v_xor_b32 %1, %1, %0\n\t"
    "v_add_u32 %0, %0, %1\n\t"
    "v_alignbit_b32 %1, %1, %1, 8\n\t"
    "v_xor_b32 %1, %1, %0\n\t"
    "v_add_u32 %1, 2, %1\n\t"
    "v_add3_u32 %0, %0, %1, %3\n\t"
    "v_alignbit_b32 %1, %1, %1, 19\n\t"
    "v_xor_b32 %1, %1, %0\n\t"
    "v_add_u32 %0, %0, %1\n\t"
    "v_alignbit_b32 %1, %1, %1, 17\n\t"
    "v_xor_b32 %1, %1, %0\n\t"
    "v_add_u32 %0, %0, %1\n\t"
    "v_alignbit_b32 %1, %1, %1, 6\n\t"
    "v_xor_b32 %1, %1, %0\n\t"
    "v_add_u32 %0, %0, %1\n\t"
    "v_alignbit_b32 %1, %1, %1, 26\n\t"
    "v_xor_b32 %1, %1, %0\n\t"
    "v_add_u32 %1, 45, %1\n\t"
    "v_add_u32 %0, %0, %1\n\t"
    "v_alignbit_b32 %1, %1, %1, 15\n\t"
    "v_xor_b32 %1, %1, %0\n\t"
    "v_add_u32 %0, %0, %1\n\t"
    "v_alignbit_b32 %1, %1, %1, 3\n\t"
    "v_xor_b32 %1, %1, %0\n\t"
    "v_add_u32 %0, %0, %1\n\t"
    "v_alignbit_b32 %1, %1, %1, 16\n\t"
    "v_xor_b32 %1, %1, %0\n\t"
    "v_add_u32 %0, %0, %1\n\t"
    "v_alignbit_b32 %1, %1, %1, 8\n\t"
    "v_xor_b32 %1, %1, %0\n\t"
    "v_add_u32 %1, 0x1bd11bf4, %1\n\t"
    "v_add3_u32 %0, %0, %1, 42\n\t"
    "v_alignbit_b32 %1, %1, %1, 19\n\t"
    "v_xor_b32 %1, %1, %0\n\t"
    "v_add_u32 %0, %0, %1\n\t"
    "v_alignbit_b32 %1, %1, %1, 17\n\t"
    "v_xor_b32 %1, %1, %0\n\t"
    "v_add_u32 %0, %0, %1\n\t"
    "v_alignbit_b32 %1, %1, %1, 6\n\t"
    "v_xor_b32 %1, %1, %0\n\t"
    "v_add_u32 %0, %0, %1\n\t"
    "v_alignbit_b32 %1, %1, %1, 26\n\t"
    "v_xor_b32 %1, %1, %0\n\t"
    "v_add_u32 %0, %3, %0\n\t"
    "v_add_u32 %1, 5, %1\n\t"
    "v_xor_b32 %0, %0, %1"
    : "=&v"(x0), "=&v"(x1)
    : "v"(m42), "s"(ks2s));
  return x0;
}

// Pre-kernel (1 block): ws[0]=max(x2), ws[1]=min(x2), ws[2]=sum_h wq[h]*wk[h]
__global__ __launch_bounds__(BLK) void prep_kernel(
    const float* __restrict__ x2, const float* __restrict__ w_q,
    const float* __restrict__ w_k, float* __restrict__ ws) {
  const int tid = threadIdx.x;
  const float4* __restrict__ x2v = (const float4*)x2;
  float mx = -3.402823466e38f, mn = 3.402823466e38f;
#pragma unroll
  for (int c4 = 0; c4 < N / 4 / BLK; ++c4) {
    float4 v = x2v[tid + c4 * BLK];
    mx = fmaxf(fmaxf(fmaxf(mx, v.x), fmaxf(v.y, v.z)), v.w);
    mn = fminf(fminf(fminf(mn, v.x), fminf(v.y, v.z)), v.w);
  }
#pragma unroll
  for (int off = 32; off > 0; off >>= 1) {
    mx = fmaxf(mx, __shfl_down(mx, off));
    mn = fminf(mn, __shfl_down(mn, off));
  }
  __shared__ float smx[NWAVES], smn[NWAVES];
  if ((tid & 63) == 0) { smx[tid >> 6] = mx; smn[tid >> 6] = mn; }
  __syncthreads();
  if (tid == 0) {
    mx = smx[0]; mn = smn[0];
    for (int w = 1; w < NWAVES; ++w) {
      mx = fmaxf(mx, smx[w]);
      mn = fminf(mn, smn[w]);
    }
    float c = 0.f;
#pragma unroll
    for (int h = 0; h < NH; ++h) c += w_q[h] * w_k[h];
    ws[0] = mx; ws[1] = mn; ws[2] = c;
  }
}

// One block per output row i.  out[i,h] = w_v[h] * S_i / (0.9 * Z_i)
__global__ __launch_bounds__(BLK) void fused_attn_kernel(
    const float* __restrict__ x1, const float* __restrict__ x2,
    const float* __restrict__ w_v, const float* __restrict__ ws,
    float* __restrict__ out) {
  const int tid = threadIdx.x;
  const int i = blockIdx.x;
  const unsigned ks2 = 0x1BD11BF0u;  // uniform -> SGPR

  const float mx = ws[0], mn = ws[1], c = ws[2];
  const float a   = c * x1[i];
  const float a2  = a * 1.4426950408889634f;       // exp(x) = exp2(x*log2e)
  const float nm2 = -((a >= 0.f ? mx : mn) * a2);  // -(row max), exp2 domain

  const float4* __restrict__ x2v = (const float4*)x2;
  const float4* __restrict__ x1v = (const float4*)x1;

  float zacc = 0.f, sacc = 0.f;
  // RNG counter for element (i, j): m42 = i*N + j + 42 (ks1 folded)
  const unsigned mb = (unsigned)i * (unsigned)N + 42u + 4u * (unsigned)tid;

#pragma unroll
  for (int c4 = 0; c4 < N / 4 / BLK; ++c4) {
    const int j4 = tid + c4 * BLK;
    const float4 xv = x2v[j4];
    const float4 yv = x1v[j4];
    const unsigned m0 = mb + (unsigned)(4 * BLK * c4);

    {
      float p = __builtin_amdgcn_exp2f(fmaf(a2, xv.x, nm2));
      zacc += p;
      float t = (tf_bits_asm(m0 + 0u, ks2) < 0xE6666600u) ? yv.x : 0.f;
      sacc = fmaf(p, t, sacc);
    }
    {
      float p = __builtin_amdgcn_exp2f(fmaf(a2, xv.y, nm2));
      zacc += p;
      float t = (tf_bits_asm(m0 + 1u, ks2) < 0xE6666600u) ? yv.y : 0.f;
      sacc = fmaf(p, t, sacc);
    }
    {
      float p = __builtin_amdgcn_exp2f(fmaf(a2, xv.z, nm2));
      zacc += p;
      float t = (tf_bits_asm(m0 + 2u, ks2) < 0xE6666600u) ? yv.z : 0.f;
      sacc = fmaf(p, t, sacc);
    }
    {
      float p = __builtin_amdgcn_exp2f(fmaf(a2, xv.w, nm2));
      zacc += p;
      float t = (tf_bits_asm(m0 + 3u, ks2) < 0xE6666600u) ? yv.w : 0.f;
      sacc = fmaf(p, t, sacc);
    }
  }

#pragma unroll
  for (int off = 32; off > 0; off >>= 1) {
    zacc += __shfl_down(zacc, off);
    sacc += __shfl_down(sacc, off);
  }
  __shared__ float sz[NWAVES], ss[NWAVES], st;
  if ((tid & 63) == 0) { sz[tid >> 6] = zacc; ss[tid >> 6] = sacc; }
  __syncthreads();
  if (tid == 0) {
    float z = 0.f, s = 0.f;
    for (int w = 0; w < NWAVES; ++w) { z += sz[w]; s += ss[w]; }
    st = s / (0.9f * z);
  }
  __syncthreads();
  if (tid < NH) out[i * NH + tid] = w_v[tid] * st;
}

extern "C" void kernel_launch(void* const* d_in, const int* in_sizes, int n_in,
                              void* d_out, int out_size, void* d_ws, size_t ws_size,
                              hipStream_t stream) {
  const float* x1  = (const float*)d_in[0];
  const float* x2  = (const float*)d_in[1];
  const float* w_q = (const float*)d_in[2];
  const float* w_k = (const float*)d_in[3];
  const float* w_v = (const float*)d_in[4];
  float* out = (float*)d_out;
  float* ws  = (float*)d_ws;
  prep_kernel<<<dim3(1), dim3(BLK), 0, stream>>>(x2, w_q, w_k, ws);
  fused_attn_kernel<<<dim3(N), dim3(BLK), 0, stream>>>(x1, x2, w_v, ws, out);
}